// Round 11
// baseline (201.366 us; speedup 1.0000x reference)
//
#include <hip/hip_runtime.h>

// LinearCRF: mean_b( logZ_b - gold_b ), B=8192, L=1024, S=3.
// Scaled linear-domain forward: lane owns a 16-step chunk, 3x3 transfer
// matrix product with exact pow2 renorm; 6-stage shfl_xor butterfly
// composes 64 chunks per wave (1 wave = 1 seq/iter). Gold fused.
// R14: COALESCED gll->LDS STAGING, barrier-free, pipelined.
// Decisive R13 clue: warm-cache replays (hbm_bytes 4MB) run at the SAME
// 68.5us as cold -- duration invariant to data source. The cost is
// request PROCESSING: AoS loads touch 64 distinct lines/instr (1280
// line-touches/wave @ ~3.5cy/touch/CU = the 60us crf_loads wall).
// Coalesced layout = 320 touches. R4 failed via lgkmcnt(0) full-drain
// serialization + confounds; here: per-wave 20KB LDS slab, 20x
// global_load_lds (coalesced, no dest VGPR, unsinkable), wave-local
// vmcnt waits ONLY (no __syncthreads in loop), persistent 4-seq loop
// pipelines stage(n+1) under compute(n). Owner reads: E stride 192B,
// MK/TG stride 64B -> 2-way bank alias = free (m136). Body = R10 verbatim.
// 512 blocks x 80KB LDS = exactly 2 blocks/CU.

#define LOG2E 1.4426950408889634f
#define LN2   0.6931471805599453f

constexpr int B = 8192;
constexpr int L = 1024;
constexpr int SEQS_PER_BLOCK = 4;     // 4 waves of 64 per block
constexpr int NBLK = 512;             // 2048 waves, 4 seqs each
constexpr int ITERS = B / (NBLK * SEQS_PER_BLOCK);  // 4
// Per-wave LDS slab layout (float4 units): em[768] | mask[256] | tags[256]
constexpr int SLAB = 1280;            // 20 KB per wave

__device__ __forceinline__ float fexp2(float x) { return __builtin_amdgcn_exp2f(x); }
__device__ __forceinline__ float flog2(float x) { return __builtin_amdgcn_logf(x); }

__device__ __forceinline__ float f4get(const float4& v, int c) {
  return c == 0 ? v.x : (c == 1 ? v.y : (c == 2 ? v.z : v.w));
}
__device__ __forceinline__ int i4get(const int4& v, int c) {
  return c == 0 ? v.x : (c == 1 ? v.y : (c == 2 ? v.z : v.w));
}

__device__ __forceinline__ float mux3(float x0, float x1, float x2, int i) {
  return (i == 0) ? x0 : ((i == 1) ? x1 : x2);
}
// transitions[p][c] via cndmask chain (no dynamic register indexing)
__device__ __forceinline__ float trmux(const float* __restrict__ T2, int p, int c) {
  const float r0 = mux3(T2[0], T2[1], T2[2], c);
  const float r1 = mux3(T2[3], T2[4], T2[5], c);
  const float r2 = mux3(T2[6], T2[7], T2[8], c);
  return mux3(r0, r1, r2, p);
}

__device__ __forceinline__ void matmul3(float* __restrict__ D,
                                        const float* __restrict__ A,
                                        const float* __restrict__ Bm) {
  #pragma unroll
  for (int i = 0; i < 3; ++i)
    #pragma unroll
    for (int j = 0; j < 3; ++j)
      D[i * 3 + j] = A[i * 3 + 0] * Bm[0 * 3 + j] +
                     A[i * 3 + 1] * Bm[1 * 3 + j] +
                     A[i * 3 + 2] * Bm[2 * 3 + j];
}

// Exact power-of-2 renormalization: P *= 2^-ex, scale += ex.
__device__ __forceinline__ void renorm3(float* __restrict__ P, float& scale) {
  float m = P[0];
  #pragma unroll
  for (int e = 1; e < 9; ++e) m = fmaxf(m, P[e]);
  int ex;
  (void)frexpf(m, &ex);
  #pragma unroll
  for (int e = 0; e < 9; ++e) P[e] = ldexpf(P[e], -ex);
  scale += (float)ex;
}

// Issue the 20 coalesced global_load_lds for sequence b into this wave's slab.
// Each instr: lane i -> slab[base + 64u + i] (HW dest = uniform base + lane*16).
__device__ __forceinline__ void stage_seq(
    float4* slab, const float* em, const float* mask, const int* tags,
    int b, int lane) {
  const float4* emG = (const float4*)em + (size_t)b * 768;
  const float4* mkG = (const float4*)mask + (size_t)b * 256;
  const float4* tgG = (const float4*)tags + (size_t)b * 256;
  #pragma unroll
  for (int u = 0; u < 12; ++u)
    __builtin_amdgcn_global_load_lds(
        (const __attribute__((address_space(1))) void*)(emG + 64 * u + lane),
        (__attribute__((address_space(3))) void*)(slab + 64 * u), 16, 0, 0);
  #pragma unroll
  for (int u = 0; u < 4; ++u)
    __builtin_amdgcn_global_load_lds(
        (const __attribute__((address_space(1))) void*)(mkG + 64 * u + lane),
        (__attribute__((address_space(3))) void*)(slab + 768 + 64 * u), 16, 0, 0);
  #pragma unroll
  for (int u = 0; u < 4; ++u)
    __builtin_amdgcn_global_load_lds(
        (const __attribute__((address_space(1))) void*)(tgG + 64 * u + lane),
        (__attribute__((address_space(3))) void*)(slab + 1024 + 64 * u), 16, 0, 0);
}

__global__ __launch_bounds__(256, 2) void crf_main(
    const float* __restrict__ em, const float* __restrict__ mask,
    const float* __restrict__ trans, const int* __restrict__ tags,
    float* __restrict__ ws) {
  const int lane = threadIdx.x & 63;
  const int wid = threadIdx.x >> 6;
  const int gwid = blockIdx.x * SEQS_PER_BLOCK + wid;   // [0, 2048)

  __shared__ float4 sBuf[SEQS_PER_BLOCK][SLAB];   // 80 KB: 20 KB per wave
  __shared__ float red[SEQS_PER_BLOCK];
  float4* slab = &sBuf[wid][0];

  // Transitions: log2 domain + linear form (uniform, loop-invariant).
  float T2[9], tk[9];
  #pragma unroll
  for (int e = 0; e < 9; ++e) {
    T2[e] = trans[e] * LOG2E;
    tk[e] = fexp2(T2[e]);
  }

  // Prologue: stage seq 0 (in flight during T2/tk setup above is fine too).
  stage_seq(slab, em, mask, tags, gwid, lane);

  float wsum = 0.f;   // lane 0 accumulates (logZ - gold) over ITERS seqs

  #pragma unroll 1
  for (int it = 0; it < ITERS; ++it) {
    // Wave-local: our slab's 20 loads are complete. (No barrier: each wave
    // touches only its own slab.)
    asm volatile("s_waitcnt vmcnt(0)" ::: "memory");

    // ---- fill registers from LDS (owner-lane patterns, 2-way alias=free) ----
    float4 E[12];
    #pragma unroll
    for (int v = 0; v < 12; ++v) E[v] = slab[12 * lane + v];
    float4 MK[4];
    #pragma unroll
    for (int u = 0; u < 4; ++u) MK[u] = slab[768 + 4 * lane + u];
    int4 TG[4];
    #pragma unroll
    for (int u = 0; u < 4; ++u)
      TG[u] = *reinterpret_cast<const int4*>(&slab[1024 + 4 * lane + u]);

    // All LDS reads complete before the slab is overwritten by next stage.
    asm volatile("s_waitcnt lgkmcnt(0)" ::: "memory");
    __builtin_amdgcn_sched_barrier(0);

    // ---- stage next sequence under this one's compute ----
    if (it + 1 < ITERS)
      stage_seq(slab, em, mask, tags, (it + 1) * (NBLK * SEQS_PER_BLOCK) + gwid,
                lane);

    // ---- compute (R10 body verbatim) ----
    float P[9] = {1.f, 0.f, 0.f, 0.f, 1.f, 0.f, 0.f, 0.f, 1.f};
    float scale = 0.f, gold = 0.f;
    float a0 = 0.f, a1 = 0.f, a2 = 0.f;   // step-0 linear emissions (lane 0)
    float e0_sel = 0.f, mk0 = 0.f;        // deferred step-0 gold term
    int tag0 = 0, prev = 0;

    #pragma unroll
    for (int s = 0; s < 16; ++s) {
      const float ev0 = f4get(E[(3 * s + 0) >> 2], (3 * s + 0) & 3) * LOG2E;
      const float ev1 = f4get(E[(3 * s + 1) >> 2], (3 * s + 1) & 3) * LOG2E;
      const float ev2 = f4get(E[(3 * s + 2) >> 2], (3 * s + 2) & 3) * LOG2E;
      const float m   = f4get(MK[s >> 2], s & 3);
      const int   cur = i4get(TG[s >> 2], s & 3);

      // ---- gold score (log2 domain) ----
      const float e = mux3(ev0, ev1, ev2, cur);
      if (s == 0) {
        e0_sel = e; mk0 = m; tag0 = cur;  // cross-lane prev tag fixed up later
      } else {
        gold = fmaf(trmux(T2, prev, cur) + e, m, gold);
      }
      prev = cur;

      // ---- matrix step (linear domain): M = act ? tk.*w : I ----
      const float w0 = fexp2(ev0);
      const float w1 = fexp2(ev1);
      const float w2 = fexp2(ev2);
      if (s == 0) { a0 = w0; a1 = w1; a2 = w2; }
      const bool act = (m > 0.f) && !(s == 0 && lane == 0);  // t=0 is alpha0
      const float g  = act ? 1.f : 0.f;
      const float c1 = 1.f - g;
      const float u0 = w0 * g, u1 = w1 * g, u2 = w2 * g;
      float M[9];
      M[0] = fmaf(tk[0], u0, c1); M[1] = tk[1] * u1;           M[2] = tk[2] * u2;
      M[3] = tk[3] * u0;          M[4] = fmaf(tk[4], u1, c1);  M[5] = tk[5] * u2;
      M[6] = tk[6] * u0;          M[7] = tk[7] * u1;           M[8] = fmaf(tk[8], u2, c1);
      float N[9];
      matmul3(N, P, M);
      #pragma unroll
      for (int e2 = 0; e2 < 9; ++e2) P[e2] = N[e2];

      if (s == 7 || s == 15) renorm3(P, scale);  // bound fp32 range
    }

    // ---- deferred step-0 gold term (needs previous lane's last tag) ----
    const int prevLast = __shfl_up(prev, 1);
    if (lane == 0) gold = fmaf(e0_sel, mk0, gold);
    else           gold = fmaf(trmux(T2, prevLast, tag0) + e0_sel, mk0, gold);
    #pragma unroll
    for (int d = 1; d < 64; d <<= 1) gold += __shfl_xor(gold, d, 64);

    // ---- ordered butterfly combine (entries <= 3^6=729: no renorm) ----
    #pragma unroll
    for (int d = 1; d < 64; d <<= 1) {
      float o[9];
      #pragma unroll
      for (int e = 0; e < 9; ++e) o[e] = __shfl_xor(P[e], d, 64);
      const float osc = __shfl_xor(scale, d, 64);
      const bool later = (lane & d) != 0;  // self covers the later segment
      float A[9], Bm[9];
      #pragma unroll
      for (int e = 0; e < 9; ++e) {
        A[e]  = later ? o[e] : P[e];
        Bm[e] = later ? P[e] : o[e];
      }
      float N[9];
      matmul3(N, A, Bm);
      #pragma unroll
      for (int e = 0; e < 9; ++e) P[e] = N[e];
      scale += osc;
    }

    // ---- per-seq finalize: accumulate on lane 0 ----
    if (lane == 0) {
      const float z = a0 * (P[0] + P[1] + P[2]) +
                      a1 * (P[3] + P[4] + P[5]) +
                      a2 * (P[6] + P[7] + P[8]);
      wsum += LN2 * (scale + flog2(z) - gold);
    }
  }

  // ---- block partial -> workspace (one store per block, no atomic) ----
  if (lane == 0) red[wid] = wsum;
  __syncthreads();
  if (threadIdx.x == 0) {
    ws[blockIdx.x] = red[0] + red[1] + red[2] + red[3];
  }
}

// Reduce 512 block partials -> mean. One block, no atomics.
__global__ __launch_bounds__(256) void crf_reduce(
    const float* __restrict__ ws, float* __restrict__ out) {
  const int t = threadIdx.x;
  const float4* w4 = (const float4*)ws;   // 512 floats = 128 float4
  float s = 0.f;
  if (t < 128) {
    const float4 v = w4[t];
    s = (v.x + v.y) + (v.z + v.w);
  }
  #pragma unroll
  for (int d = 1; d < 64; d <<= 1) s += __shfl_xor(s, d, 64);
  __shared__ float red[4];
  if ((t & 63) == 0) red[t >> 6] = s;
  __syncthreads();
  if (t == 0) out[0] = (red[0] + red[1] + red[2] + red[3]) * (1.0f / (float)B);
}

extern "C" void kernel_launch(void* const* d_in, const int* in_sizes, int n_in,
                              void* d_out, int out_size, void* d_ws, size_t ws_size,
                              hipStream_t stream) {
  const float* em    = (const float*)d_in[0];
  const float* mask  = (const float*)d_in[1];
  const float* trans = (const float*)d_in[2];
  const int*   tags  = (const int*)d_in[3];
  float* out = (float*)d_out;
  float* ws  = (float*)d_ws;

  crf_main<<<NBLK, 256, 0, stream>>>(em, mask, trans, tags, ws);
  crf_reduce<<<1, 256, 0, stream>>>(ws, out);
}